// Round 11
// baseline (333.464 us; speedup 1.0000x reference)
//
#include <hip/hip_runtime.h>
#include <hip/hip_bf16.h>

typedef unsigned short u16;
typedef __attribute__((ext_vector_type(8))) short short8;
typedef __attribute__((ext_vector_type(16))) float f32x16;

#define B_  64
#define T_  512
#define H_  1024
#define U_  1024
#define BT_ (B_*T_)

#define BM 256
#define BN 256
#define BK 32

// async global->LDS, 16B per lane, wave-uniform LDS base (HW adds lane*16)
#define GLL16(gp, lp) __builtin_amdgcn_global_load_lds( \
    (const __attribute__((address_space(1))) void*)(gp), \
    (__attribute__((address_space(3))) void*)(lp), 16, 0, 0)

template<int N>
__device__ __forceinline__ void vwait() {
  asm volatile("s_waitcnt vmcnt(%0)" :: "n"(N) : "memory");
}

__device__ __forceinline__ u16 f32_to_bf16(float f) {
  union { float f; unsigned u; } v; v.f = f;
  unsigned r = v.u + 0x7FFFu + ((v.u >> 16) & 1u);
  return (u16)(r >> 16);
}
__device__ __forceinline__ unsigned pack_bf16x2(float lo, float hi) {
  return (unsigned)f32_to_bf16(lo) | ((unsigned)f32_to_bf16(hi) << 16);
}

// ---- prep: enc f32->bf16 (blocks 0..16383), Wh transpose->bf16 (blocks
// 16384..17407), score zeroing (blocks 0..127 double duty) ----
__global__ __launch_bounds__(256) void ba_prep(const float4* __restrict__ in,
                                               uint4* __restrict__ out,
                                               const float* __restrict__ wh,
                                               u16* __restrict__ whT,
                                               float* __restrict__ score) {
  __shared__ float tile[32][33];
  const int bx = blockIdx.x;
  const int tid = threadIdx.x;
  if (bx < 16384) {
    int i = bx * 256 + tid;
    float4 v0 = in[2 * i], v1 = in[2 * i + 1];
    uint4 o;
    o.x = pack_bf16x2(v0.x, v0.y);
    o.y = pack_bf16x2(v0.z, v0.w);
    o.z = pack_bf16x2(v1.x, v1.y);
    o.w = pack_bf16x2(v1.z, v1.w);
    out[i] = o;
    if (bx < 128) score[bx * 256 + tid] = 0.f;
  } else {
    int wb = bx - 16384;
    int u0 = (wb & 31) * 32, h0 = (wb >> 5) * 32;
    int tx = tid & 31, ty = tid >> 5;  // 32 x 8
    #pragma unroll
    for (int i = 0; i < 32; i += 8)
      tile[ty + i][tx] = wh[(long)(h0 + ty + i) * U_ + u0 + tx];
    __syncthreads();
    #pragma unroll
    for (int i = 0; i < 32; i += 8)
      whT[(long)(u0 + ty + i) * H_ + h0 + tx] = f32_to_bf16(tile[tx][ty + i]);
  }
}

// ---- fused GEMM + tanh + dot(Wv) -> score[B*T] ----
// A = enc bf16 [32768][1024] (M x K), Bt = WhT bf16 [1024][1024] (N x K)
// grid (128, 4): 256x256 block tile; 512 threads = 8 waves (2 wm x 4 wn),
// wave tile 128x64. mfma_f32_32x32x16_bf16 (half the MFMA instruction
// count vs 16x16x32, same FLOP) -> frags mf=4 (M), nf=2 (N),
// 2 k-steps (k=16 each) per BK=32 tile. acc[4][2] f32x16.
// Same deep pipeline as R8: 4 LDS buffers, depth-3 prefetch, vmcnt(8) at
// tile top (never 0 until tail), ONE s_barrier per K-tile, setprio around
// MFMA clusters, stage of tile t+3 split across the two k-phases.
// LDS rows 64B (32 bf16), rotation swizzle phys_slot(r,l) = (l+(r>>1))&3,
// pre-applied on the GLOBAL source column at stage (LDS write linear) and
// on the read slot. For both MFMA shapes the read-row rotation reduces to
// (lane>>1)&3 (row = multiple-of-4 + (lane&31) or (lane&15)).
__global__ __launch_bounds__(512, 2) void ba_score(
    const u16* __restrict__ A, const u16* __restrict__ Bt,
    const float* __restrict__ bh, const float* __restrict__ wv,
    float* __restrict__ score) {
  __shared__ u16 lA[4][BM * BK];   // 4 x 16 KB
  __shared__ u16 lB[4][BN * BK];   // 4 x 16 KB

  const int tid  = threadIdx.x;    // 0..511
  const int wid  = tid >> 6;       // 0..7
  const int lane = tid & 63;
  const int wm = wid >> 2;         // 0..1 -> M half (128 rows)
  const int wn = wid & 3;          // 0..3 -> N quarter (64 cols)
  const long row0  = (long)blockIdx.x * BM;
  const int  ncol0 = blockIdx.y * BN;

  // staging: each issue = 512 thr x 16B = 8 KB = 128 rows of 64B.
  // thread -> row tid>>2, phys slot tid&3; fetch logical (s - rot)&3
  const int srow = tid >> 2;
  const int csw  = (((tid & 3) - ((tid >> 3) & 3)) & 3) * 8;

  // 32x32x16 fragment addressing: lane l holds row/col (l&31),
  // k8-group (l>>5); logical slot = ks*2 + (l>>5); rot = (lane>>1)&3.
  const int l31 = lane & 31;
  const int rowA = (wm * 128 + l31) * BK;  // + mf*1024, u16 units
  const int rowB = (wn * 64  + l31) * BK;  // + nf*1024
  const int s0 = (((lane >> 5) + ((lane >> 1) & 3)) & 3) * 8;  // ks=0 slot
  // ks=1 slot: (+2 mod 4) -> s0 ^ 16 (u16 units)

  const u16* gA = A  + (row0 + srow) * H_ + csw;
  const u16* gB = Bt + (long)(ncol0 + srow) * H_ + csw;

  f32x16 acc[4][2];
  #pragma unroll
  for (int i = 0; i < 4; ++i)
    #pragma unroll
    for (int j = 0; j < 2; ++j)
      #pragma unroll
      for (int r = 0; r < 16; ++r) acc[i][j][r] = 0.f;

#define STAGEF(t_, b_) do { \
    const long _k = (long)(t_) * BK; \
    GLL16(gA + _k,            (char*)lA[b_] + wid * 1024); \
    GLL16(gA + 128 * H_ + _k, (char*)lA[b_] + 8192 + wid * 1024); \
    GLL16(gB + _k,            (char*)lB[b_] + wid * 1024); \
    GLL16(gB + 128 * H_ + _k, (char*)lB[b_] + 8192 + wid * 1024); \
  } while (0)

#define TILE(t_, WAITN, DO_STAGE) do { \
    const int _bt = (t_) & 3; \
    vwait<WAITN>(); \
    __builtin_amdgcn_sched_barrier(0); \
    __builtin_amdgcn_s_barrier(); \
    __builtin_amdgcn_sched_barrier(0); \
    short8 af[4], bfr[2]; \
    _Pragma("unroll") \
    for (int mf = 0; mf < 4; ++mf) \
      af[mf] = *(const short8*)&lA[_bt][rowA + mf * 1024 + s0]; \
    _Pragma("unroll") \
    for (int nf = 0; nf < 2; ++nf) \
      bfr[nf] = *(const short8*)&lB[_bt][rowB + nf * 1024 + s0]; \
    if (DO_STAGE) { \
      const long _k = (long)((t_) + 3) * BK; \
      const int _nb = ((t_) + 3) & 3; \
      GLL16(gA + _k,            (char*)lA[_nb] + wid * 1024); \
      GLL16(gA + 128 * H_ + _k, (char*)lA[_nb] + 8192 + wid * 1024); \
    } \
    __builtin_amdgcn_s_setprio(1); \
    _Pragma("unroll") \
    for (int mf = 0; mf < 4; ++mf) \
      _Pragma("unroll") \
      for (int nf = 0; nf < 2; ++nf) \
        acc[mf][nf] = __builtin_amdgcn_mfma_f32_32x32x16_bf16(af[mf], bfr[nf], acc[mf][nf], 0, 0, 0); \
    __builtin_amdgcn_s_setprio(0); \
    _Pragma("unroll") \
    for (int mf = 0; mf < 4; ++mf) \
      af[mf] = *(const short8*)&lA[_bt][rowA + mf * 1024 + (s0 ^ 16)]; \
    _Pragma("unroll") \
    for (int nf = 0; nf < 2; ++nf) \
      bfr[nf] = *(const short8*)&lB[_bt][rowB + nf * 1024 + (s0 ^ 16)]; \
    if (DO_STAGE) { \
      const long _k = (long)((t_) + 3) * BK; \
      const int _nb = ((t_) + 3) & 3; \
      GLL16(gB + _k,            (char*)lB[_nb] + wid * 1024); \
      GLL16(gB + 128 * H_ + _k, (char*)lB[_nb] + 8192 + wid * 1024); \
    } \
    __builtin_amdgcn_s_setprio(1); \
    _Pragma("unroll") \
    for (int mf = 0; mf < 4; ++mf) \
      _Pragma("unroll") \
      for (int nf = 0; nf < 2; ++nf) \
        acc[mf][nf] = __builtin_amdgcn_mfma_f32_32x32x16_bf16(af[mf], bfr[nf], acc[mf][nf], 0, 0, 0); \
    __builtin_amdgcn_s_setprio(0); \
  } while (0)

  // prologue: 3 K-tiles in flight (12 outstanding loads per thread)
  STAGEF(0, 0);
  STAGEF(1, 1);
  STAGEF(2, 2);

  for (int t = 0; t < 30; ++t) {
    TILE(t, 8, t < 29);   // steady state: wait tile t, 8 loads still flying
  }
  TILE(30, 4, false);
  TILE(31, 0, false);
#undef TILE
#undef STAGEF

  // epilogue: x = D + bh[n]; sloc += tanh(x) * wv[n]; reduce over the
  // 32-lane n-group; atomicAdd per output row (lanes 0 and 32 hold the
  // two 4*(lane>>5) row-halves). 16 contributors per score element.
  float sloc[4][16];
  #pragma unroll
  for (int mf = 0; mf < 4; ++mf)
    #pragma unroll
    for (int r = 0; r < 16; ++r) sloc[mf][r] = 0.f;

  #pragma unroll
  for (int nf = 0; nf < 2; ++nf) {
    const int n = ncol0 + wn * 64 + nf * 32 + l31;
    const float bhn = bh[n];
    const float wvn = wv[n];
    #pragma unroll
    for (int mf = 0; mf < 4; ++mf) {
      #pragma unroll
      for (int r = 0; r < 16; ++r) {
        float x = acc[mf][nf][r] + bhn;
        float e = __expf(2.f * x);
        sloc[mf][r] += (1.f - 2.f / (e + 1.f)) * wvn;
      }
    }
  }

  #pragma unroll
  for (int mf = 0; mf < 4; ++mf) {
    #pragma unroll
    for (int r = 0; r < 16; ++r) {
      float v = sloc[mf][r];
      v += __shfl_xor(v, 1);
      v += __shfl_xor(v, 2);
      v += __shfl_xor(v, 4);
      v += __shfl_xor(v, 8);
      v += __shfl_xor(v, 16);
      if (l31 == 0) {
        long m = row0 + wm * 128 + mf * 32 + (r & 3) + 8 * (r >> 2) + 4 * (lane >> 5);
        atomicAdd(&score[m], v);
      }
    }
  }
}

// ---- context stage 1 + fused softmax ----
// grid (64, 16): each block redundantly computes the row softmax stats
// (bitwise identical across blocks), block c==0 writes attn_out, then
// reduces its 32-t chunk of attn*enc into part. NO atomics.
__global__ __launch_bounds__(256) void ba_context1(const float4* __restrict__ enc4,
                                                   const float* __restrict__ score,
                                                   float* __restrict__ attn_out,
                                                   float4* __restrict__ part) {
  __shared__ float redm[4], reds[4];
  __shared__ float atile[32];
  int b = blockIdx.x, c = blockIdx.y, tid = threadIdx.x;
  int lane = tid & 63, wid = tid >> 6;
  const float* s = score + b * T_;
  float v0 = s[tid], v1 = s[tid + 256];
  float m = fmaxf(v0, v1);
  #pragma unroll
  for (int o = 1; o < 64; o <<= 1) m = fmaxf(m, __shfl_xor(m, o));
  if (lane == 0) redm[wid] = m;
  __syncthreads();
  m = fmaxf(fmaxf(redm[0], redm[1]), fmaxf(redm[2], redm[3]));
  float e0 = __expf(v0 - m), e1 = __expf(v1 - m);
  float sum = e0 + e1;
  #pragma unroll
  for (int o = 1; o < 64; o <<= 1) sum += __shfl_xor(sum, o);
  if (lane == 0) reds[wid] = sum;
  __syncthreads();
  float inv = 1.f / (reds[0] + reds[1] + reds[2] + reds[3]);

  if (c == 0) {
    attn_out[b * T_ + tid] = e0 * inv;
    attn_out[b * T_ + tid + 256] = e1 * inv;
  }
  // publish this block's 32 attn values to LDS
  int base = c * 32;
  if (base < 256) {
    if (tid >= base && tid < base + 32) atile[tid - base] = e0 * inv;
  } else {
    int bb = base - 256;
    if (tid >= bb && tid < bb + 32) atile[tid - bb] = e1 * inv;
  }
  __syncthreads();

  const float4* e = enc4 + ((long)b * T_ + base) * (H_ / 4) + tid;
  float4 acc = {0.f, 0.f, 0.f, 0.f};
  #pragma unroll 4
  for (int t = 0; t < 32; ++t) {
    float4 v = e[(long)t * (H_ / 4)];
    float at = atile[t];
    acc.x = fmaf(at, v.x, acc.x);
    acc.y = fmaf(at, v.y, acc.y);
    acc.z = fmaf(at, v.z, acc.z);
    acc.w = fmaf(at, v.w, acc.w);
  }
  part[((long)b * 16 + c) * (H_ / 4) + tid] = acc;
}

// ---- context stage 2: ctx[b][h] = sum_c partial[b][c][h]; grid 64 ----
__global__ __launch_bounds__(256) void ba_context2(const float4* __restrict__ part,
                                                   float4* __restrict__ ctx) {
  int b = blockIdx.x;
  int tid = threadIdx.x;
  const float4* p = part + (long)b * 16 * (H_ / 4) + tid;
  float4 acc = {0.f, 0.f, 0.f, 0.f};
  #pragma unroll
  for (int c = 0; c < 16; ++c) {
    float4 v = p[c * (H_ / 4)];
    acc.x += v.x; acc.y += v.y; acc.z += v.z; acc.w += v.w;
  }
  ctx[b * (H_ / 4) + tid] = acc;
}

extern "C" void kernel_launch(void* const* d_in, const int* in_sizes, int n_in,
                              void* d_out, int out_size, void* d_ws, size_t ws_size,
                              hipStream_t stream) {
  // inputs: 0 dec_hidden (unused: softmax shift-invariance), 1 enc_output,
  //         2 Wh, 3 bh, 4 Ws (unused), 5 bs (unused), 6 Wv, 7 bv (unused)
  const float* enc = (const float*)d_in[1];
  const float* Wh  = (const float*)d_in[2];
  const float* bh  = (const float*)d_in[3];
  const float* Wv  = (const float*)d_in[6];

  float* out      = (float*)d_out;
  float* ctx_out  = out;             // [64][1024]
  float* attn_out = out + B_ * H_;   // [64][512]

  char* ws = (char*)d_ws;
  u16*   encb  = (u16*)ws;                                       // 67108864 B
  u16*   whT   = (u16*)(ws + (size_t)67108864);                  //  2097152 B
  float* score = (float*)(ws + (size_t)67108864 + 2097152);      //   131072 B
  float* part  = (float*)(ws + (size_t)67108864 + 2097152 + 131072); // 4 MB

  ba_prep<<<16384 + 1024, 256, 0, stream>>>((const float4*)enc, (uint4*)encb,
                                            Wh, whT, score);
  ba_score<<<dim3(BT_ / BM, U_ / BN), 512, 0, stream>>>(encb, whT, bh, Wv, score);
  ba_context1<<<dim3(B_, 16), 256, 0, stream>>>((const float4*)enc, score,
                                                attn_out, (float4*)part);
  ba_context2<<<B_, 256, 0, stream>>>((const float4*)part, (float4*)ctx_out);
}